// Round 5
// baseline (37.986 us; speedup 1.0000x reference)
//
#include <hip/hip_runtime.h>
#include <hip/hip_bf16.h>

// out[8192,1024] = x[8192,1024] @ W[1024,1024]^T + b  (fp32 in/out, bf16 MFMA)
// v5: BM=256 x BN=128, BK=32, 512 thr / 8 waves as 4Mx2N (wave tile 64x64,
// acc[4][4] -> 0.5 LDS-reads/MFMA), grid 256 = exactly 1 block/CU.
// XCD-exclusive m-panels; v3/v4-verified zero-conflict LDS swizzle; depth-1
// register prefetch; one barrier per K-step. 48KB static LDS.

typedef float f32x4 __attribute__((ext_vector_type(4)));
typedef __bf16 bf16x8 __attribute__((ext_vector_type(8)));
typedef unsigned short u16x4 __attribute__((ext_vector_type(4)));
typedef unsigned short u16x8 __attribute__((ext_vector_type(8)));

#define MD 8192
#define ND 1024
#define KD 1024
#define BM 256
#define BN 128
#define BK 32
#define NT (KD / BK)     // 32 K-steps
#define THREADS 512

__device__ __forceinline__ u16x4 cvt4(f32x4 v) {
  u16x4 o;
#pragma unroll
  for (int i = 0; i < 4; ++i) o[i] = __builtin_bit_cast(unsigned short, (__bf16)v[i]);
  return o;
}

__global__ __launch_bounds__(THREADS, 2)
void linear_mfma_v5(const float* __restrict__ X, const float* __restrict__ W,
                    const float* __restrict__ Bv, float* __restrict__ C) {
  // 16-row stripes of 1024B; within-stripe byte = ((kq<<8)+(r16<<4)+(h<<3)) ^ (kq<<5)
  // (kq = k>>3, h = (k>>2)&1). Verified conflict-free write + read (v3/v4: 0 conflicts).
  __shared__ __align__(16) char Asm[2][BM * BK * 2];   // 16 KB each
  __shared__ __align__(16) char Bsm[2][BN * BK * 2];   // 8 KB each

  const int bid = blockIdx.x;
  const int xcd = bid & 7;                 // dispatch round-robins XCDs by bid&7
  const int ord = bid >> 3;                // 0..31
  const int mtile = xcd * 4 + (ord >> 3);  // 4 XCD-exclusive m-panels per XCD
  const int ntile = ord & 7;
  const int brow = mtile * BM;
  const int bcol = ntile * BN;

  const int t = threadIdx.x;
  const int lane = t & 63;
  const int w = t >> 6;      // 0..7
  const int wm = w >> 1;     // 0..3 : 64-row quarter of BM=256
  const int wn = w & 1;      // 0..1 : 64-col half of BN=128

  // ---- staging map: q -> (row = q>>3, sc = q&7); f32x4 chunk at k = sc*4
  const float* gA[4]; int woffA[4];
#pragma unroll
  for (int i = 0; i < 4; ++i) {
    int q = t + i * THREADS;               // 0..2047 -> 256 rows x 8 chunks
    int row = q >> 3, sc = q & 7;
    int kq = sc >> 1, h = sc & 1;
    gA[i] = X + (size_t)(brow + row) * KD + sc * 4;
    woffA[i] = (row >> 4) * 1024 + ((((kq << 8) + ((row & 15) << 4) + (h << 3))) ^ (kq << 5));
  }
  const float* gB[2]; int woffB[2];
#pragma unroll
  for (int i = 0; i < 2; ++i) {
    int q = t + i * THREADS;               // 0..1023 -> 128 rows x 8 chunks
    int row = q >> 3, sc = q & 7;
    int kq = sc >> 1, h = sc & 1;
    gB[i] = W + (size_t)(bcol + row) * KD + sc * 4;
    woffB[i] = (row >> 4) * 1024 + ((((kq << 8) + ((row & 15) << 4) + (h << 3))) ^ (kq << 5));
  }

  // fragment read offset within a 1KB stripe (16B/lane, swizzle-mirrored)
  const int fr = (lane * 16) ^ ((lane >> 4) << 5);

  f32x4 pa[4], pb[2];

#define LOADT(kt)                                                        \
  do {                                                                   \
    _Pragma("unroll") for (int i = 0; i < 4; ++i)                        \
        pa[i] = *(const f32x4*)(gA[i] + (size_t)(kt) * BK);              \
    _Pragma("unroll") for (int i = 0; i < 2; ++i)                        \
        pb[i] = *(const f32x4*)(gB[i] + (size_t)(kt) * BK);              \
  } while (0)

#define WRITET(buf)                                                      \
  do {                                                                   \
    _Pragma("unroll") for (int i = 0; i < 4; ++i)                        \
        *(u16x4*)&Asm[buf][woffA[i]] = cvt4(pa[i]);                      \
    _Pragma("unroll") for (int i = 0; i < 2; ++i)                        \
        *(u16x4*)&Bsm[buf][woffB[i]] = cvt4(pb[i]);                      \
  } while (0)

  f32x4 acc[4][4] = {};

#define COMPUTE(buf)                                                           \
  do {                                                                         \
    bf16x8 bf[4];                                                              \
    _Pragma("unroll") for (int n = 0; n < 4; ++n)                              \
      bf[n] = __builtin_bit_cast(bf16x8,                                       \
          *(const u16x8*)(&Bsm[buf][(wn * 4 + n) * 1024 + fr]));               \
    _Pragma("unroll") for (int m = 0; m < 4; ++m) {                            \
      bf16x8 am = __builtin_bit_cast(bf16x8,                                   \
          *(const u16x8*)(&Asm[buf][(wm * 4 + m) * 1024 + fr]));               \
      _Pragma("unroll") for (int n = 0; n < 4; ++n)                            \
        acc[m][n] = __builtin_amdgcn_mfma_f32_16x16x32_bf16(am, bf[n],         \
                                                            acc[m][n], 0, 0, 0); \
    }                                                                          \
  } while (0)

  // ---- prologue
  LOADT(0);
  WRITET(0);
  __syncthreads();

  // ---- main loop: one barrier per K-step
#pragma unroll 1
  for (int kt = 0; kt < NT; ++kt) {
    if (kt + 1 < NT) LOADT(kt + 1);        // issue next-tile loads early
    COMPUTE(kt & 1);
    if (kt + 1 < NT) {
      WRITET((kt + 1) & 1);                // cvt + stage next tile
      __syncthreads();
    }
  }

  // ---- epilogue: C/D layout col = lane&15, row = (lane>>4)*4 + j  [m89]
  const int rbase = brow + wm * 64 + ((lane >> 4) << 2);
  const int cbase = bcol + wn * 64 + (lane & 15);
#pragma unroll
  for (int n = 0; n < 4; ++n) {
    const int col = cbase + n * 16;
    const float bv = Bv[col];
#pragma unroll
    for (int m = 0; m < 4; ++m) {
      const int row = rbase + m * 16;
#pragma unroll
      for (int j = 0; j < 4; ++j) {
        C[(size_t)(row + j) * ND + col] = acc[m][n][j] + bv;
      }
    }
  }
}

extern "C" void kernel_launch(void* const* d_in, const int* in_sizes, int n_in,
                              void* d_out, int out_size, void* d_ws, size_t ws_size,
                              hipStream_t stream) {
  const float* x = (const float*)d_in[0];   // [8192,1024] f32
  const float* W = (const float*)d_in[1];   // [1024,1024] f32
  const float* b = (const float*)d_in[2];   // [1024] f32
  float* out = (float*)d_out;               // [8192,1024] f32

  dim3 grid((MD / BM) * (ND / BN));   // 32 * 8 = 256 blocks = 1 per CU
  dim3 block(THREADS);
  hipLaunchKernelGGL(linear_mfma_v5, grid, block, 0, stream, x, W, b, out);
}

// Round 6
// 34.161 us; speedup vs baseline: 1.1120x; 1.1120x over previous
//
#include <hip/hip_runtime.h>
#include <hip/hip_bf16.h>

// out[8192,1024] = x[8192,1024] @ W[1024,1024]^T + b  (fp32 in/out, bf16 MFMA)
// v6: BM=BN=128, BK=32, 256 thr / 4 waves (2x2, wave tile 64x64 = 0.5 LDS reads
// per MFMA), LDS 32KB/block -> 2 independent blocks per CU (m114 overlap).
// Depth-2 named-set register prefetch (loads issued a full K-step before use ->
// counted vmcnt, latency hidden by construction). XCD-exclusive m-panels,
// verified zero-conflict LDS swizzle, write-late (T14), setprio around MFMA.

typedef float f32x4 __attribute__((ext_vector_type(4)));
typedef __bf16 bf16x8 __attribute__((ext_vector_type(8)));
typedef unsigned short u16x4 __attribute__((ext_vector_type(4)));
typedef unsigned short u16x8 __attribute__((ext_vector_type(8)));

#define MD 8192
#define ND 1024
#define KD 1024
#define BM 128
#define BN 128
#define BK 32
#define NT (KD / BK)     // 32 K-steps
#define THREADS 256

__device__ __forceinline__ u16x4 cvt4(f32x4 v) {
  u16x4 o;
#pragma unroll
  for (int i = 0; i < 4; ++i) o[i] = __builtin_bit_cast(unsigned short, (__bf16)v[i]);
  return o;
}

__global__ __launch_bounds__(THREADS, 2)
void linear_mfma_v6(const float* __restrict__ X, const float* __restrict__ W,
                    const float* __restrict__ Bv, float* __restrict__ C) {
  // 16-row stripes of 1024B; within-stripe byte = ((kq<<8)+(r16<<4)+(h<<3)) ^ (kq<<5)
  // (kq=k>>3, h=(k>>2)&1). Verified conflict-free write+read (v3..v5: 0 conflicts).
  __shared__ __align__(16) char Asm[2][BM * BK * 2];   // 8 KB each
  __shared__ __align__(16) char Bsm[2][BN * BK * 2];   // 8 KB each

  const int bid = blockIdx.x;
  const int xcd = bid & 7;                 // dispatch round-robins XCDs by bid&7
  const int ord = bid >> 3;                // 0..63
  const int mtile = xcd * 8 + (ord >> 3);  // 8 XCD-exclusive m-panels per XCD
  const int ntile = ord & 7;
  const int brow = mtile * BM;
  const int bcol = ntile * BN;

  const int t = threadIdx.x;
  const int lane = t & 63;
  const int w = t >> 6;      // 0..3
  const int wm = w >> 1;     // 0..1 : 64-row half
  const int wn = w & 1;      // 0..1 : 64-col half

  // ---- staging map: q = t + i*256 -> (row = q>>3, sc = q&7); f32x4 at k = sc*4
  const float* gA[4];
  const float* gB[4];
  int woff[4];
#pragma unroll
  for (int i = 0; i < 4; ++i) {
    int q = t + i * THREADS;               // 0..1023 -> 128 rows x 8 chunks
    int row = q >> 3, sc = q & 7;
    int kq = sc >> 1, h = sc & 1;
    gA[i] = X + (size_t)(brow + row) * KD + sc * 4;
    gB[i] = W + (size_t)(bcol + row) * KD + sc * 4;
    woff[i] = (row >> 4) * 1024 + ((((kq << 8) + ((row & 15) << 4) + (h << 3))) ^ (kq << 5));
  }

  // fragment read offset within a 1KB stripe (16B/lane, swizzle-mirrored)
  const int fr = (lane * 16) ^ ((lane >> 4) << 5);

  // depth-2 prefetch register sets (literal set index only -> stays in registers)
  f32x4 pa0[4], pb0[4], pa1[4], pb1[4];

#define LOADSET0(kt)                                                      \
  do {                                                                    \
    _Pragma("unroll") for (int i = 0; i < 4; ++i)                         \
        pa0[i] = *(const f32x4*)(gA[i] + (size_t)(kt) * BK);              \
    _Pragma("unroll") for (int i = 0; i < 4; ++i)                         \
        pb0[i] = *(const f32x4*)(gB[i] + (size_t)(kt) * BK);              \
  } while (0)
#define LOADSET1(kt)                                                      \
  do {                                                                    \
    _Pragma("unroll") for (int i = 0; i < 4; ++i)                         \
        pa1[i] = *(const f32x4*)(gA[i] + (size_t)(kt) * BK);              \
    _Pragma("unroll") for (int i = 0; i < 4; ++i)                         \
        pb1[i] = *(const f32x4*)(gB[i] + (size_t)(kt) * BK);              \
  } while (0)

#define WRITESET0(buf)                                                    \
  do {                                                                    \
    _Pragma("unroll") for (int i = 0; i < 4; ++i)                         \
        *(u16x4*)&Asm[buf][woff[i]] = cvt4(pa0[i]);                       \
    _Pragma("unroll") for (int i = 0; i < 4; ++i)                         \
        *(u16x4*)&Bsm[buf][woff[i]] = cvt4(pb0[i]);                       \
  } while (0)
#define WRITESET1(buf)                                                    \
  do {                                                                    \
    _Pragma("unroll") for (int i = 0; i < 4; ++i)                         \
        *(u16x4*)&Asm[buf][woff[i]] = cvt4(pa1[i]);                       \
    _Pragma("unroll") for (int i = 0; i < 4; ++i)                         \
        *(u16x4*)&Bsm[buf][woff[i]] = cvt4(pb1[i]);                       \
  } while (0)

  f32x4 acc[4][4] = {};

#define COMPUTE(buf)                                                           \
  do {                                                                         \
    bf16x8 bf[4];                                                              \
    _Pragma("unroll") for (int n = 0; n < 4; ++n)                              \
      bf[n] = __builtin_bit_cast(bf16x8,                                       \
          *(const u16x8*)(&Bsm[buf][(wn * 4 + n) * 1024 + fr]));               \
    bf16x8 am[4];                                                              \
    _Pragma("unroll") for (int m = 0; m < 4; ++m)                              \
      am[m] = __builtin_bit_cast(bf16x8,                                       \
          *(const u16x8*)(&Asm[buf][(wm * 4 + m) * 1024 + fr]));               \
    __builtin_amdgcn_s_setprio(1);                                             \
    _Pragma("unroll") for (int m = 0; m < 4; ++m)                              \
      _Pragma("unroll") for (int n = 0; n < 4; ++n)                            \
        acc[m][n] = __builtin_amdgcn_mfma_f32_16x16x32_bf16(am[m], bf[n],      \
                                                            acc[m][n], 0, 0, 0); \
    __builtin_amdgcn_s_setprio(0);                                             \
  } while (0)

  // ---- prologue: set0 <- tile0, set1 <- tile1, stage tile0, sync
  LOADSET0(0);
  LOADSET1(1);
  WRITESET0(0);          // waits only set0's loads (vmcnt(8)); set1 stays in flight
  __syncthreads();

  // ---- main loop: 2 K-steps per iteration, one barrier each
#pragma unroll 1
  for (int kt2 = 0; kt2 < NT / 2; ++kt2) {
    // EVEN step kt = 2*kt2 (reads buf0); set0 free -> prefetch tile kt+2
    if (kt2 < NT / 2 - 1) LOADSET0(2 * kt2 + 2);
    COMPUTE(0);
    WRITESET1(1);                          // stage tile kt+1 (loaded 1 step ago)
    __syncthreads();

    // ODD step kt = 2*kt2+1 (reads buf1); set1 free -> prefetch tile kt+3
    if (kt2 < NT / 2 - 1) LOADSET1(2 * kt2 + 3);
    COMPUTE(1);
    if (kt2 < NT / 2 - 1) {
      WRITESET0(0);                        // stage tile kt+2
      __syncthreads();
    }
  }

  // ---- epilogue: C/D layout col = lane&15, row = (lane>>4)*4 + j  [m89]
  const int rbase = brow + wm * 64 + ((lane >> 4) << 2);
  const int cbase = bcol + wn * 64 + (lane & 15);
#pragma unroll
  for (int n = 0; n < 4; ++n) {
    const int col = cbase + n * 16;
    const float bv = Bv[col];
#pragma unroll
    for (int m = 0; m < 4; ++m) {
      const int row = rbase + m * 16;
#pragma unroll
      for (int j = 0; j < 4; ++j) {
        C[(size_t)(row + j) * ND + col] = acc[m][n][j] + bv;
      }
    }
  }
}

extern "C" void kernel_launch(void* const* d_in, const int* in_sizes, int n_in,
                              void* d_out, int out_size, void* d_ws, size_t ws_size,
                              hipStream_t stream) {
  const float* x = (const float*)d_in[0];   // [8192,1024] f32
  const float* W = (const float*)d_in[1];   // [1024,1024] f32
  const float* b = (const float*)d_in[2];   // [1024] f32
  float* out = (float*)d_out;               // [8192,1024] f32

  dim3 grid((MD / BM) * (ND / BN));   // 64 * 8 = 512 -> 2 blocks per CU
  dim3 block(THREADS);
  hipLaunchKernelGGL(linear_mfma_v6, grid, block, 0, stream, x, W, b, out);
}